// Round 1
// baseline (139.758 us; speedup 1.0000x reference)
//
#include <hip/hip_runtime.h>
#include <math.h>

// Problem geometry (fixed by the reference)
#define NIMG 16
#define IH 768
#define IW 1024
#define HD 384          // downsampled H
#define WD 512          // downsampled W
#define TH 16           // tile height (output pixels)
#define TW 64           // tile width  (output pixels)
#define HALO 3
#define RH (TH + 2*HALO)   // 22 rows of pooled input per tile
#define RW (TW + 2*HALO)   // 70 cols of pooled input per tile
#define RWP 72             // padded row stride (multiple of 4 -> 16B aligned float4)
#define NGX (WD/TW)        // 8
#define NGY (HD/TH)        // 24
#define NBLK (NGX*NGY*NIMG) // 3072
#define SSIM_C1 1.0e-4f
#define SSIM_C2 9.0e-4f

struct GW { float g[7]; };

// Fused: 2x2 avg-pool -> separable 7x7 gaussian blur of {p,t,pp,tt,pt}
// -> SSIM map -> per-block partial sum.
__global__ __launch_bounds__(256, 4) void ssim_main(
    const float* __restrict__ pred, const float* __restrict__ tgt,
    float* __restrict__ partial, GW gw)
{
  __shared__ float p_s[RH][RWP];
  __shared__ float t_s[RH][RWP];
  __shared__ float vb[5][TH][RWP];   // vertically-blurred {p,t,pp,tt,pt}
  __shared__ float wred[4];

  const int tid = threadIdx.x;
  const int bx = blockIdx.x, by = blockIdx.y, n = blockIdx.z;
  const int tx0 = bx * TW, ty0 = by * TH;
  const float* __restrict__ pb = pred + (size_t)n * IH * IW;
  const float* __restrict__ tb = tgt  + (size_t)n * IH * IW;

  // ---- Phase A: 2x2 avg-pool into LDS (halo = 3, zero pad outside) ----
  for (int idx = tid; idx < RH * RW; idx += 256) {
    const int ly = idx / RW;
    const int lx = idx - ly * RW;
    const int gy = ty0 + ly - HALO;
    const int gx = tx0 + lx - HALO;
    float pv = 0.f, tv = 0.f;
    if ((unsigned)gy < (unsigned)HD && (unsigned)gx < (unsigned)WD) {
      const size_t o0 = (size_t)(2 * gy) * IW + (size_t)(2 * gx);
      const float2 a = *(const float2*)(pb + o0);
      const float2 b = *(const float2*)(pb + o0 + IW);
      const float2 c = *(const float2*)(tb + o0);
      const float2 d = *(const float2*)(tb + o0 + IW);
      pv = 0.25f * ((a.x + a.y) + (b.x + b.y));
      tv = 0.25f * ((c.x + c.y) + (d.x + d.y));
    }
    p_s[ly][lx] = pv;
    t_s[ly][lx] = tv;
  }
  __syncthreads();

  // ---- Phase B: vertical 7-tap blur of {p, t, p*p, t*t, p*t} ----
  // squares/products formed in registers; float4 LDS traffic throughout
  for (int idx = tid; idx < TH * (RWP/4); idx += 256) {
    const int y  = idx / (RWP/4);
    const int c4 = (idx - y * (RWP/4)) * 4;
    float m1_0=0,m1_1=0,m1_2=0,m1_3=0;
    float m2_0=0,m2_1=0,m2_2=0,m2_3=0;
    float pp_0=0,pp_1=0,pp_2=0,pp_3=0;
    float tt_0=0,tt_1=0,tt_2=0,tt_3=0;
    float pt_0=0,pt_1=0,pt_2=0,pt_3=0;
#pragma unroll
    for (int k = 0; k < 7; ++k) {
      const float w = gw.g[k];
      const float4 P = *(const float4*)&p_s[y + k][c4];
      const float4 T = *(const float4*)&t_s[y + k][c4];
      m1_0 += w*P.x;        m1_1 += w*P.y;        m1_2 += w*P.z;        m1_3 += w*P.w;
      m2_0 += w*T.x;        m2_1 += w*T.y;        m2_2 += w*T.z;        m2_3 += w*T.w;
      pp_0 += w*(P.x*P.x);  pp_1 += w*(P.y*P.y);  pp_2 += w*(P.z*P.z);  pp_3 += w*(P.w*P.w);
      tt_0 += w*(T.x*T.x);  tt_1 += w*(T.y*T.y);  tt_2 += w*(T.z*T.z);  tt_3 += w*(T.w*T.w);
      pt_0 += w*(P.x*T.x);  pt_1 += w*(P.y*T.y);  pt_2 += w*(P.z*T.z);  pt_3 += w*(P.w*T.w);
    }
    *(float4*)&vb[0][y][c4] = make_float4(m1_0, m1_1, m1_2, m1_3);
    *(float4*)&vb[1][y][c4] = make_float4(m2_0, m2_1, m2_2, m2_3);
    *(float4*)&vb[2][y][c4] = make_float4(pp_0, pp_1, pp_2, pp_3);
    *(float4*)&vb[3][y][c4] = make_float4(tt_0, tt_1, tt_2, tt_3);
    *(float4*)&vb[4][y][c4] = make_float4(pt_0, pt_1, pt_2, pt_3);
  }
  __syncthreads();

  // ---- Phase C: horizontal 7-tap blur + SSIM + local sum ----
  float lsum = 0.f;
  for (int idx = tid; idx < TH * (TW/4); idx += 256) {
    const int y  = idx / (TW/4);
    const int c0 = (idx - y * (TW/4)) * 4;
    // 12-wide windows per channel, kept in registers (all indices constant)
    float w0[12], w1[12], w2[12], w3[12], w4[12];
#define LDCH(arr, ch) { \
      const float4 A = *(const float4*)&vb[ch][y][c0];     \
      const float4 B = *(const float4*)&vb[ch][y][c0 + 4]; \
      const float4 C = *(const float4*)&vb[ch][y][c0 + 8]; \
      arr[0]=A.x; arr[1]=A.y; arr[2]=A.z;  arr[3]=A.w;     \
      arr[4]=B.x; arr[5]=B.y; arr[6]=B.z;  arr[7]=B.w;     \
      arr[8]=C.x; arr[9]=C.y; arr[10]=C.z; arr[11]=C.w; }
    LDCH(w0, 0) LDCH(w1, 1) LDCH(w2, 2) LDCH(w3, 3) LDCH(w4, 4)
#undef LDCH
#pragma unroll
    for (int j = 0; j < 4; ++j) {
      float mu1 = 0.f, mu2 = 0.f, bpp = 0.f, btt = 0.f, bpt = 0.f;
#pragma unroll
      for (int k = 0; k < 7; ++k) {
        const float w = gw.g[k];
        mu1 += w * w0[j + k];
        mu2 += w * w1[j + k];
        bpp += w * w2[j + k];
        btt += w * w3[j + k];
        bpt += w * w4[j + k];
      }
      const float mu1sq = mu1 * mu1;
      const float mu2sq = mu2 * mu2;
      const float mu12  = mu1 * mu2;
      const float s1    = bpp - mu1sq;
      const float s2    = btt - mu2sq;
      const float s12   = bpt - mu12;
      const float num = (2.f * mu12 + SSIM_C1) * (2.f * s12 + SSIM_C2);
      const float den = (mu1sq + mu2sq + SSIM_C1) * (s1 + s2 + SSIM_C2);
      lsum += num / (den + 1e-12f);
    }
  }

  // ---- Phase D: block reduction -> one partial per block ----
#pragma unroll
  for (int off = 32; off > 0; off >>= 1)
    lsum += __shfl_down(lsum, off, 64);
  if ((tid & 63) == 0) wred[tid >> 6] = lsum;
  __syncthreads();
  if (tid == 0)
    partial[((size_t)n * NGY + by) * NGX + bx] =
        wred[0] + wred[1] + wred[2] + wred[3];
}

__global__ __launch_bounds__(256) void ssim_final(
    const float* __restrict__ partial, float* __restrict__ out)
{
  __shared__ float red[4];
  float s = 0.f;
  for (int i = threadIdx.x; i < NBLK; i += 256) s += partial[i];
#pragma unroll
  for (int off = 32; off > 0; off >>= 1)
    s += __shfl_down(s, off, 64);
  if ((threadIdx.x & 63) == 0) red[threadIdx.x >> 6] = s;
  __syncthreads();
  if (threadIdx.x == 0) {
    const float tot = red[0] + red[1] + red[2] + red[3];
    out[0] = 1.0f - tot * (1.0f / (float)((size_t)NIMG * HD * WD));
  }
}

extern "C" void kernel_launch(void* const* d_in, const int* in_sizes, int n_in,
                              void* d_out, int out_size, void* d_ws, size_t ws_size,
                              hipStream_t stream) {
  const float* pred = (const float*)d_in[0];
  const float* tgt  = (const float*)d_in[1];
  float* out     = (float*)d_out;
  float* partial = (float*)d_ws;   // NBLK floats of scratch

  // Gaussian window (matches reference: sigma=1.5, 7 taps, normalized)
  GW gw;
  double gd[7], s = 0.0;
  for (int i = 0; i < 7; ++i) {
    const double x = (double)i - 3.0;
    gd[i] = exp(-x * x / (2.0 * 1.5 * 1.5));
    s += gd[i];
  }
  for (int i = 0; i < 7; ++i) gw.g[i] = (float)(gd[i] / s);

  dim3 grid(NGX, NGY, NIMG);
  ssim_main<<<grid, 256, 0, stream>>>(pred, tgt, partial, gw);
  ssim_final<<<1, 256, 0, stream>>>(partial, out);
}

// Round 3
// 134.185 us; speedup vs baseline: 1.0415x; 1.0415x over previous
//
#include <hip/hip_runtime.h>
#include <math.h>

// Problem geometry (fixed by the reference)
#define NIMG 16
#define IH 768
#define IW 1024
#define HD 384          // downsampled H
#define WD 512          // downsampled W
#define TH 16           // tile height (output pixels)
#define TW 64           // tile width  (output pixels)
#define HALO_Y 3
#define HALO_X 4           // widened to 4 so input float4 loads are 16B-aligned
#define RH (TH + 2*HALO_Y)   // 22 pooled rows per tile
#define RW (TW + 2*HALO_X)   // 72 pooled cols per tile (= padded stride, uniform)
#define NPAIR (RW/2)         // 36 column-pairs per row
#define NSLOT (RH*NPAIR)     // 792 load slots
#define NGX (WD/TW)          // 8
#define NGY (HD/TH)          // 24
#define NBLK (NGX*NGY*NIMG)  // 3072
#define SSIM_C1 1.0e-4f
#define SSIM_C2 9.0e-4f

struct GW { float g[7]; };

// Fused: 2x2 avg-pool -> LDS -> per-thread separable 7x7 blur of
// {p,t,pp,tt,pt} (vertical in registers, recomputed per thread) -> SSIM
// -> per-block partial sum.  LDS = 2*22*72*4 = 12.7 KB -> high occupancy.
__global__ __launch_bounds__(256, 5) void ssim_main(
    const float* __restrict__ pred, const float* __restrict__ tgt,
    float* __restrict__ partial, GW gw)
{
  __shared__ float p_s[RH][RW];
  __shared__ float t_s[RH][RW];
  __shared__ float wred[4];

  const int tid = threadIdx.x;
  const int bx = blockIdx.x, by = blockIdx.y, n = blockIdx.z;
  const int tx0 = bx * TW, ty0 = by * TH;
  const float* __restrict__ pb = pred + (size_t)n * IH * IW;
  const float* __restrict__ tb = tgt  + (size_t)n * IH * IW;

  // ---- Phase A: 2x2 avg-pool into LDS, aligned float4 global loads ----
  // slot -> (row, pair): pooled row = ty0 + row - 3, pooled col pair base
  // = tx0 - 4 + 2*pair (always even; pair is entirely in- or out-of-range).
#pragma unroll
  for (int i = 0; i < 4; ++i) {
    const int slot = tid + i * 256;
    if (slot < NSLOT) {
      const int row  = slot / NPAIR;
      const int pair = slot - row * NPAIR;
      const int gy = ty0 + row - HALO_Y;           // pooled row
      const int pg = tx0 + 2 * pair - HALO_X;      // pooled col (even)
      float pv0 = 0.f, pv1 = 0.f, tv0 = 0.f, tv1 = 0.f;
      if ((unsigned)gy < (unsigned)HD && (unsigned)pg < (unsigned)WD) {
        const size_t o0 = (size_t)(2 * gy) * IW + (size_t)(2 * pg);
        const float4 a = *(const float4*)(pb + o0);
        const float4 b = *(const float4*)(pb + o0 + IW);
        const float4 c = *(const float4*)(tb + o0);
        const float4 d = *(const float4*)(tb + o0 + IW);
        pv0 = 0.25f * ((a.x + a.y) + (b.x + b.y));
        pv1 = 0.25f * ((a.z + a.w) + (b.z + b.w));
        tv0 = 0.25f * ((c.x + c.y) + (d.x + d.y));
        tv1 = 0.25f * ((c.z + c.w) + (d.z + d.w));
      }
      *(float2*)&p_s[row][2 * pair] = make_float2(pv0, pv1);
      *(float2*)&t_s[row][2 * pair] = make_float2(tv0, tv1);
    }
  }
  __syncthreads();

  // ---- Phase B: fused vertical+horizontal blur + SSIM ----
  // thread -> output row y (16 rows x 16 threads), 4 consecutive cols c0..c0+3.
  // Output col c maps to LDS col c+HALO_X-3 = c+1; window = LDS cols c+1..c+7.
  // 12-wide aligned register window covers LDS cols c0..c0+11.
  const int y  = tid >> 4;          // 0..15
  const int c0 = (tid & 15) << 2;   // 0..60

  float a1[12], a2[12], app[12], att[12], apt[12];
#pragma unroll
  for (int i = 0; i < 12; ++i) { a1[i]=0.f; a2[i]=0.f; app[i]=0.f; att[i]=0.f; apt[i]=0.f; }

#pragma unroll
  for (int k = 0; k < 7; ++k) {
    const float w = gw.g[k];
#pragma unroll
    for (int g = 0; g < 3; ++g) {
      const float4 P = *(const float4*)&p_s[y + k][c0 + 4 * g];
      const float4 T = *(const float4*)&t_s[y + k][c0 + 4 * g];
      const int b = 4 * g;
      a1[b+0] = fmaf(w, P.x, a1[b+0]);  a1[b+1] = fmaf(w, P.y, a1[b+1]);
      a1[b+2] = fmaf(w, P.z, a1[b+2]);  a1[b+3] = fmaf(w, P.w, a1[b+3]);
      a2[b+0] = fmaf(w, T.x, a2[b+0]);  a2[b+1] = fmaf(w, T.y, a2[b+1]);
      a2[b+2] = fmaf(w, T.z, a2[b+2]);  a2[b+3] = fmaf(w, T.w, a2[b+3]);
      app[b+0] = fmaf(w, P.x*P.x, app[b+0]);  app[b+1] = fmaf(w, P.y*P.y, app[b+1]);
      app[b+2] = fmaf(w, P.z*P.z, app[b+2]);  app[b+3] = fmaf(w, P.w*P.w, app[b+3]);
      att[b+0] = fmaf(w, T.x*T.x, att[b+0]);  att[b+1] = fmaf(w, T.y*T.y, att[b+1]);
      att[b+2] = fmaf(w, T.z*T.z, att[b+2]);  att[b+3] = fmaf(w, T.w*T.w, att[b+3]);
      apt[b+0] = fmaf(w, P.x*T.x, apt[b+0]);  apt[b+1] = fmaf(w, P.y*T.y, apt[b+1]);
      apt[b+2] = fmaf(w, P.z*T.z, apt[b+2]);  apt[b+3] = fmaf(w, P.w*T.w, apt[b+3]);
    }
  }

  float lsum = 0.f;
#pragma unroll
  for (int j = 0; j < 4; ++j) {
    float mu1 = 0.f, mu2 = 0.f, bpp = 0.f, btt = 0.f, bpt = 0.f;
#pragma unroll
    for (int k = 0; k < 7; ++k) {
      const float w = gw.g[k];
      const int idx = j + 1 + k;      // LDS-col offset within the 12-window
      mu1 = fmaf(w, a1[idx],  mu1);
      mu2 = fmaf(w, a2[idx],  mu2);
      bpp = fmaf(w, app[idx], bpp);
      btt = fmaf(w, att[idx], btt);
      bpt = fmaf(w, apt[idx], bpt);
    }
    const float mu1sq = mu1 * mu1;
    const float mu2sq = mu2 * mu2;
    const float mu12  = mu1 * mu2;
    const float s1    = bpp - mu1sq;
    const float s2    = btt - mu2sq;
    const float s12   = bpt - mu12;
    const float num = (2.f * mu12 + SSIM_C1) * (2.f * s12 + SSIM_C2);
    const float den = (mu1sq + mu2sq + SSIM_C1) * (s1 + s2 + SSIM_C2);
    lsum += num / (den + 1e-12f);
  }

  // ---- Phase C: block reduction -> one partial per block ----
#pragma unroll
  for (int off = 32; off > 0; off >>= 1)
    lsum += __shfl_down(lsum, off, 64);
  if ((tid & 63) == 0) wred[tid >> 6] = lsum;
  __syncthreads();
  if (tid == 0)
    partial[((size_t)n * NGY + by) * NGX + bx] =
        wred[0] + wred[1] + wred[2] + wred[3];
}

__global__ __launch_bounds__(256) void ssim_final(
    const float* __restrict__ partial, float* __restrict__ out)
{
  __shared__ float red[4];
  float s = 0.f;
  for (int i = threadIdx.x; i < NBLK; i += 256) s += partial[i];
#pragma unroll
  for (int off = 32; off > 0; off >>= 1)
    s += __shfl_down(s, off, 64);
  if ((threadIdx.x & 63) == 0) red[threadIdx.x >> 6] = s;
  __syncthreads();
  if (threadIdx.x == 0) {
    const float tot = red[0] + red[1] + red[2] + red[3];
    out[0] = 1.0f - tot * (1.0f / (float)((size_t)NIMG * HD * WD));
  }
}

extern "C" void kernel_launch(void* const* d_in, const int* in_sizes, int n_in,
                              void* d_out, int out_size, void* d_ws, size_t ws_size,
                              hipStream_t stream) {
  const float* pred = (const float*)d_in[0];
  const float* tgt  = (const float*)d_in[1];
  float* out     = (float*)d_out;
  float* partial = (float*)d_ws;   // NBLK floats of scratch

  // Gaussian window (matches reference: sigma=1.5, 7 taps, normalized)
  GW gw;
  double gd[7], s = 0.0;
  for (int i = 0; i < 7; ++i) {
    const double x = (double)i - 3.0;
    gd[i] = exp(-x * x / (2.0 * 1.5 * 1.5));
    s += gd[i];
  }
  for (int i = 0; i < 7; ++i) gw.g[i] = (float)(gd[i] / s);

  dim3 grid(NGX, NGY, NIMG);
  ssim_main<<<grid, 256, 0, stream>>>(pred, tgt, partial, gw);
  ssim_final<<<1, 256, 0, stream>>>(partial, out);
}

// Round 9
// 127.435 us; speedup vs baseline: 1.0967x; 1.0530x over previous
//
#include <hip/hip_runtime.h>
#include <math.h>

// Problem geometry (fixed by the reference)
#define NIMG 16
#define IH 768
#define IW 1024
#define HD 384          // downsampled H
#define WD 512          // downsampled W
#define TH 16           // tile height (output pixels)
#define TW 64           // tile width  (output pixels)
#define HALO_Y 3
#define HALO_X 4             // widened to 4 so input float4 loads are 16B-aligned
#define RH (TH + 2*HALO_Y)   // 22 pooled rows per tile
#define RW (TW + 2*HALO_X)   // 72 pooled data cols per tile
#define RWS 74               // row stride (pad 2): keeps float2 writes 8B-aligned
#define NPAIR (RW/2)         // 36 column-pairs per row
#define NSLOT (RH*NPAIR)     // 792 load slots
#define NGX (WD/TW)          // 8
#define NGY (HD/TH)          // 24
#define NBLK (NGX*NGY*NIMG)  // 3072
#define SSIM_C1 1.0e-4f
#define SSIM_C2 9.0e-4f

struct GW { float g[7]; };

// Fused: 2x2 avg-pool -> LDS -> horizontal 7-tap blur of {p,t,pp,tt,pt}
// (lane = column; uniform row per LDS read instr -> conflict-free) ->
// on-the-fly vertical 7-tap accumulation -> SSIM -> per-block partial sum.
__global__ __launch_bounds__(256, 4) void ssim_main(
    const float* __restrict__ pred, const float* __restrict__ tgt,
    float* __restrict__ partial, GW gw)
{
  __shared__ float p_s[RH][RWS];
  __shared__ float t_s[RH][RWS];
  __shared__ float wred[4];

  const int tid = threadIdx.x;
  const int bx = blockIdx.x, by = blockIdx.y, n = blockIdx.z;
  const int tx0 = bx * TW, ty0 = by * TH;
  const float* __restrict__ pb = pred + (size_t)n * IH * IW;
  const float* __restrict__ tb = tgt  + (size_t)n * IH * IW;

  // ---- Phase A: 2x2 avg-pool into LDS, aligned float4 global loads ----
#pragma unroll
  for (int i = 0; i < 4; ++i) {
    const int slot = tid + i * 256;
    if (slot < NSLOT) {
      const int row  = slot / NPAIR;
      const int pair = slot - row * NPAIR;
      const int gy = ty0 + row - HALO_Y;           // pooled row
      const int pg = tx0 + 2 * pair - HALO_X;      // pooled col (even)
      float pv0 = 0.f, pv1 = 0.f, tv0 = 0.f, tv1 = 0.f;
      if ((unsigned)gy < (unsigned)HD && (unsigned)pg < (unsigned)WD) {
        const size_t o0 = (size_t)(2 * gy) * IW + (size_t)(2 * pg);
        const float4 a = *(const float4*)(pb + o0);
        const float4 b = *(const float4*)(pb + o0 + IW);
        const float4 c = *(const float4*)(tb + o0);
        const float4 d = *(const float4*)(tb + o0 + IW);
        pv0 = 0.25f * ((a.x + a.y) + (b.x + b.y));
        pv1 = 0.25f * ((a.z + a.w) + (b.z + b.w));
        tv0 = 0.25f * ((c.x + c.y) + (d.x + d.y));
        tv1 = 0.25f * ((c.z + c.w) + (d.z + d.w));
      }
      *(float2*)&p_s[row][2 * pair] = make_float2(pv0, pv1);
      *(float2*)&t_s[row][2 * pair] = make_float2(tv0, tv1);
    }
  }
  __syncthreads();

  // ---- Phase B: horizontal blur per LDS row (lane = col), vertical on the fly
  // wave w -> output rows 4w..4w+3; needs LDS rows 4w..4w+9.
  // output col c -> LDS cols c+1..c+7 (c + HALO_X - 3).
  const int lane = tid & 63;
  const int wv   = tid >> 6;        // wave id 0..3
  const int r0   = wv * 4;          // first output row of this wave
  const int c    = lane;            // output col 0..63

  float acc0[4], acc1[4], acc2[4], acc3[4], acc4[4];
#pragma unroll
  for (int r = 0; r < 4; ++r) { acc0[r]=0.f; acc1[r]=0.f; acc2[r]=0.f; acc3[r]=0.f; acc4[r]=0.f; }

#pragma unroll
  for (int j = 0; j < 10; ++j) {
    const int lrow = r0 + j;
    const float* __restrict__ prow = &p_s[lrow][c + 1];
    const float* __restrict__ trow = &t_s[lrow][c + 1];
    float hp = 0.f, ht = 0.f, hpp = 0.f, htt = 0.f, hpt = 0.f;
#pragma unroll
    for (int k = 0; k < 7; ++k) {
      const float wk = gw.g[k];
      const float p = prow[k];
      const float t = trow[k];
      const float wp = wk * p;
      const float wt = wk * t;
      hp += wp;
      ht += wt;
      hpp = fmaf(wp, p, hpp);
      htt = fmaf(wt, t, htt);
      hpt = fmaf(wp, t, hpt);
    }
    // vertical accumulation: hb row j feeds output rows r with 0<=j-r<7
#pragma unroll
    for (int r = 0; r < 4; ++r) {
      const int ki = j - r;
      if (ki >= 0 && ki < 7) {
        const float wvk = gw.g[ki];
        acc0[r] = fmaf(wvk, hp,  acc0[r]);
        acc1[r] = fmaf(wvk, ht,  acc1[r]);
        acc2[r] = fmaf(wvk, hpp, acc2[r]);
        acc3[r] = fmaf(wvk, htt, acc3[r]);
        acc4[r] = fmaf(wvk, hpt, acc4[r]);
      }
    }
  }

  // ---- SSIM map + local sum over this thread's 4 outputs ----
  float lsum = 0.f;
#pragma unroll
  for (int r = 0; r < 4; ++r) {
    const float mu1 = acc0[r], mu2 = acc1[r];
    const float mu1sq = mu1 * mu1;
    const float mu2sq = mu2 * mu2;
    const float mu12  = mu1 * mu2;
    const float s1    = acc2[r] - mu1sq;
    const float s2    = acc3[r] - mu2sq;
    const float s12   = acc4[r] - mu12;
    const float num = (2.f * mu12 + SSIM_C1) * (2.f * s12 + SSIM_C2);
    const float den = (mu1sq + mu2sq + SSIM_C1) * (s1 + s2 + SSIM_C2);
    lsum += num / (den + 1e-12f);
  }

  // ---- block reduction -> one partial per block ----
#pragma unroll
  for (int off = 32; off > 0; off >>= 1)
    lsum += __shfl_down(lsum, off, 64);
  if (lane == 0) wred[wv] = lsum;
  __syncthreads();
  if (tid == 0)
    partial[((size_t)n * NGY + by) * NGX + bx] =
        wred[0] + wred[1] + wred[2] + wred[3];
}

__global__ __launch_bounds__(256) void ssim_final(
    const float* __restrict__ partial, float* __restrict__ out)
{
  __shared__ float red[4];
  float s = 0.f;
  for (int i = threadIdx.x; i < NBLK; i += 256) s += partial[i];
#pragma unroll
  for (int off = 32; off > 0; off >>= 1)
    s += __shfl_down(s, off, 64);
  if ((threadIdx.x & 63) == 0) red[threadIdx.x >> 6] = s;
  __syncthreads();
  if (threadIdx.x == 0) {
    const float tot = red[0] + red[1] + red[2] + red[3];
    out[0] = 1.0f - tot * (1.0f / (float)((size_t)NIMG * HD * WD));
  }
}

extern "C" void kernel_launch(void* const* d_in, const int* in_sizes, int n_in,
                              void* d_out, int out_size, void* d_ws, size_t ws_size,
                              hipStream_t stream) {
  const float* pred = (const float*)d_in[0];
  const float* tgt  = (const float*)d_in[1];
  float* out     = (float*)d_out;
  float* partial = (float*)d_ws;   // NBLK floats of scratch

  // Gaussian window (matches reference: sigma=1.5, 7 taps, normalized)
  GW gw;
  double gd[7], s = 0.0;
  for (int i = 0; i < 7; ++i) {
    const double x = (double)i - 3.0;
    gd[i] = exp(-x * x / (2.0 * 1.5 * 1.5));
    s += gd[i];
  }
  for (int i = 0; i < 7; ++i) gw.g[i] = (float)(gd[i] / s);

  dim3 grid(NGX, NGY, NIMG);
  ssim_main<<<grid, 256, 0, stream>>>(pred, tgt, partial, gw);
  ssim_final<<<1, 256, 0, stream>>>(partial, out);
}

// Round 10
// 124.185 us; speedup vs baseline: 1.1254x; 1.0262x over previous
//
#include <hip/hip_runtime.h>
#include <math.h>

// Problem geometry (fixed by the reference)
#define NIMG 16
#define IH 768
#define IW 1024
#define HD 384          // downsampled H
#define WD 512          // downsampled W
#define TH 32           // tile height (output pixels)
#define TW 64           // tile width  (output pixels)
#define HALO_Y 3
#define HALO_X 4             // widened to 4 so input float4 loads are 16B-aligned
#define RH (TH + 2*HALO_Y)   // 38 pooled rows per tile
#define RW (TW + 2*HALO_X)   // 72 pooled data cols per tile
#define RWS 74               // row stride in float2 units (592B: keeps b128 writes aligned)
#define NPAIR (RW/2)         // 36 col-pair (float4) slots per row
#define NSLOT (RH*NPAIR)     // 1368 load slots
#define NGX (WD/TW)          // 8
#define NGY (HD/TH)          // 12
#define NBLK (NGX*NGY*NIMG)  // 1536
#define SSIM_C1 1.0e-4f
#define SSIM_C2 9.0e-4f

struct GW { float g[7]; };

// Fused: 2x2 avg-pool -> interleaved {p,t} float2 LDS -> horizontal 7-tap
// blur of {p,t,pp,tt,pt} via ds_read_b64 (lane = column, wave-uniform row:
// conflict-free) -> on-the-fly vertical 7-tap -> SSIM -> per-block partial.
__global__ __launch_bounds__(256, 4) void ssim_main(
    const float* __restrict__ pred, const float* __restrict__ tgt,
    float* __restrict__ partial, GW gw)
{
  __shared__ float2 pt_s[RH][RWS];   // pt_s[row][col] = {p(col), t(col)}  (22.5 KB)
  __shared__ float wred[4];

  const int tid = threadIdx.x;
  const int bx = blockIdx.x, by = blockIdx.y, n = blockIdx.z;
  const int tx0 = bx * TW, ty0 = by * TH;
  const float* __restrict__ pb = pred + (size_t)n * IH * IW;
  const float* __restrict__ tb = tgt  + (size_t)n * IH * IW;

  // ---- Phase A: 2x2 avg-pool -> interleaved LDS, one ds_write_b128/slot ----
#pragma unroll
  for (int i = 0; i < 6; ++i) {
    const int slot = tid + i * 256;
    if (slot < NSLOT) {
      const int row  = slot / NPAIR;
      const int pair = slot - row * NPAIR;
      const int gy = ty0 + row - HALO_Y;           // pooled row
      const int pg = tx0 + 2 * pair - HALO_X;      // pooled col (even)
      float pv0 = 0.f, pv1 = 0.f, tv0 = 0.f, tv1 = 0.f;
      if ((unsigned)gy < (unsigned)HD && (unsigned)pg < (unsigned)WD) {
        const size_t o0 = (size_t)(2 * gy) * IW + (size_t)(2 * pg);
        const float4 a = *(const float4*)(pb + o0);
        const float4 b = *(const float4*)(pb + o0 + IW);
        const float4 c = *(const float4*)(tb + o0);
        const float4 d = *(const float4*)(tb + o0 + IW);
        pv0 = 0.25f * ((a.x + a.y) + (b.x + b.y));
        pv1 = 0.25f * ((a.z + a.w) + (b.z + b.w));
        tv0 = 0.25f * ((c.x + c.y) + (d.x + d.y));
        tv1 = 0.25f * ((c.z + c.w) + (d.z + d.w));
      }
      // {p0,t0,p1,t1} covers float2 cols 2*pair, 2*pair+1; byte addr
      // = 592*row + 16*pair -> 16B aligned -> single ds_write_b128.
      *(float4*)&pt_s[row][2 * pair] = make_float4(pv0, tv0, pv1, tv1);
    }
  }
  __syncthreads();

  // ---- Phase B: horizontal blur (7 x ds_read_b64/row), vertical on the fly
  // wave wv -> output rows 8wv..8wv+7; reads LDS rows 8wv..8wv+13.
  // output col c -> LDS float2 cols c+1..c+7 (c + HALO_X - 3).
  const int lane = tid & 63;
  const int wv   = tid >> 6;        // wave id 0..3
  const int r0   = wv * 8;          // first output row of this wave
  const int c    = lane;            // output col 0..63

  float acc0[8], acc1[8], acc2[8], acc3[8], acc4[8];
#pragma unroll
  for (int r = 0; r < 8; ++r) { acc0[r]=0.f; acc1[r]=0.f; acc2[r]=0.f; acc3[r]=0.f; acc4[r]=0.f; }

#pragma unroll
  for (int j = 0; j < 14; ++j) {
    const int lrow = r0 + j;
    const float2* __restrict__ prow = &pt_s[lrow][c + 1];
    float hp = 0.f, ht = 0.f, hpp = 0.f, htt = 0.f, hpt = 0.f;
#pragma unroll
    for (int k = 0; k < 7; ++k) {
      const float wk = gw.g[k];
      const float2 v = prow[k];          // ds_read_b64, 8B-aligned
      const float wp = wk * v.x;
      const float wt = wk * v.y;
      hp += wp;
      ht += wt;
      hpp = fmaf(wp, v.x, hpp);
      htt = fmaf(wt, v.y, htt);
      hpt = fmaf(wp, v.y, hpt);
    }
    // vertical: hb row j feeds output rows r with 0 <= j-r < 7
#pragma unroll
    for (int r = 0; r < 8; ++r) {
      const int ki = j - r;
      if (ki >= 0 && ki < 7) {
        const float wvk = gw.g[ki];
        acc0[r] = fmaf(wvk, hp,  acc0[r]);
        acc1[r] = fmaf(wvk, ht,  acc1[r]);
        acc2[r] = fmaf(wvk, hpp, acc2[r]);
        acc3[r] = fmaf(wvk, htt, acc3[r]);
        acc4[r] = fmaf(wvk, hpt, acc4[r]);
      }
    }
  }

  // ---- SSIM map + local sum over this thread's 8 outputs ----
  float lsum = 0.f;
#pragma unroll
  for (int r = 0; r < 8; ++r) {
    const float mu1 = acc0[r], mu2 = acc1[r];
    const float mu1sq = mu1 * mu1;
    const float mu2sq = mu2 * mu2;
    const float mu12  = mu1 * mu2;
    const float s1    = acc2[r] - mu1sq;
    const float s2    = acc3[r] - mu2sq;
    const float s12   = acc4[r] - mu12;
    const float num = (2.f * mu12 + SSIM_C1) * (2.f * s12 + SSIM_C2);
    const float den = (mu1sq + mu2sq + SSIM_C1) * (s1 + s2 + SSIM_C2);
    lsum += num / (den + 1e-12f);
  }

  // ---- block reduction -> one partial per block ----
#pragma unroll
  for (int off = 32; off > 0; off >>= 1)
    lsum += __shfl_down(lsum, off, 64);
  if (lane == 0) wred[wv] = lsum;
  __syncthreads();
  if (tid == 0)
    partial[((size_t)n * NGY + by) * NGX + bx] =
        wred[0] + wred[1] + wred[2] + wred[3];
}

__global__ __launch_bounds__(256) void ssim_final(
    const float* __restrict__ partial, float* __restrict__ out)
{
  __shared__ float red[4];
  float s = 0.f;
  for (int i = threadIdx.x; i < NBLK; i += 256) s += partial[i];
#pragma unroll
  for (int off = 32; off > 0; off >>= 1)
    s += __shfl_down(s, off, 64);
  if ((threadIdx.x & 63) == 0) red[threadIdx.x >> 6] = s;
  __syncthreads();
  if (threadIdx.x == 0) {
    const float tot = red[0] + red[1] + red[2] + red[3];
    out[0] = 1.0f - tot * (1.0f / (float)((size_t)NIMG * HD * WD));
  }
}

extern "C" void kernel_launch(void* const* d_in, const int* in_sizes, int n_in,
                              void* d_out, int out_size, void* d_ws, size_t ws_size,
                              hipStream_t stream) {
  const float* pred = (const float*)d_in[0];
  const float* tgt  = (const float*)d_in[1];
  float* out     = (float*)d_out;
  float* partial = (float*)d_ws;   // NBLK floats of scratch

  // Gaussian window (matches reference: sigma=1.5, 7 taps, normalized)
  GW gw;
  double gd[7], s = 0.0;
  for (int i = 0; i < 7; ++i) {
    const double x = (double)i - 3.0;
    gd[i] = exp(-x * x / (2.0 * 1.5 * 1.5));
    s += gd[i];
  }
  for (int i = 0; i < 7; ++i) gw.g[i] = (float)(gd[i] / s);

  dim3 grid(NGX, NGY, NIMG);
  ssim_main<<<grid, 256, 0, stream>>>(pred, tgt, partial, gw);
  ssim_final<<<1, 256, 0, stream>>>(partial, out);
}